// Round 4
// baseline (3905.407 us; speedup 1.0000x reference)
//
#include <hip/hip_runtime.h>
#include <hip/hip_bf16.h>

// Problem dims
#define BSZ 32
#define SSZ 512
#define ISZ 512
#define HSZ 512
#define PW  32          // workgroups per direction
// ws layout (bytes)
#define XB_OFF   0ull                       // [S][64 kc][32 b][8] ushort (bf16 bits) = 16 MB
#define HEX_OFF  (16ull << 20)              // [2 dir][2 buf][64 kc][32 b][8] ushort = 128 KB
#define CTR_OFF  (HEX_OFF + (128ull << 10)) // flags: [dir] stride 2048 dwords; 64 used per dir

typedef __attribute__((ext_vector_type(8)))  short short8;
typedef __attribute__((ext_vector_type(4)))  float f32x4;
typedef __attribute__((ext_vector_type(4)))  unsigned short us4;
typedef unsigned long long ull;

__device__ __forceinline__ unsigned short f2bf(float f) {
    union { float f; unsigned u; } v; v.f = f;
    unsigned r = v.u + 0x7fffu + ((v.u >> 16) & 1u);   // RNE
    return (unsigned short)(r >> 16);
}

__device__ __forceinline__ float sigf(float x) { return 1.0f / (1.0f + __expf(-x)); }
__device__ __forceinline__ float tanhfast(float x) {
    float a = fabsf(x);
    float e = __expf(-2.0f * a);
    float t = (1.0f - e) / (1.0f + e);
    return x < 0.0f ? -t : t;
}

// X [B][S][I] fp32 -> Xb [t][kc][b][8] bf16-bits (MFMA A-fragment friendly layout)
__global__ void k_xpose(const float* __restrict__ X, unsigned short* __restrict__ Xb) {
    int idx = blockIdx.x * 256 + threadIdx.x;     // 2^21 threads total
    int i4 = idx & 127;                           // float4 index along I
    int t  = (idx >> 7) & 511;
    int b  = idx >> 16;
    float4 v = reinterpret_cast<const float4*>(X)[idx];
    us4 o = { f2bf(v.x), f2bf(v.y), f2bf(v.z), f2bf(v.w) };
    *reinterpret_cast<us4*>(Xb + (size_t)t * 16384 + (size_t)(i4 >> 1) * 256 + b * 8 + (i4 & 1) * 4) = o;
}

__launch_bounds__(256, 1)
__global__ void k_bilstm(const float* __restrict__ Wih_f, const float* __restrict__ Whh_f,
                         const float* __restrict__ bih_f, const float* __restrict__ bhh_f,
                         const float* __restrict__ Wih_b, const float* __restrict__ Whh_b,
                         const float* __restrict__ bih_b, const float* __restrict__ bhh_b,
                         const unsigned short* __restrict__ Xb,
                         unsigned short* h_ex, unsigned* flags, float* __restrict__ out)
{
    const int tid = threadIdx.x;
    const int dir = blockIdx.x & 1;     // 0 = fwd, 1 = bwd
    const int p   = blockIdx.x >> 1;    // 0..31 : owns h-cols [16p, 16p+16)
    const int wv  = tid >> 6;
    const int ln  = tid & 63;
    const int kh  = wv >> 1;            // 0: x-projection (+ gate math), 1: h-recurrence
    const int nt  = wv & 1;             // gate-pair tile
    const int q   = ln >> 4;            // quad within wave
    const int m15 = ln & 15;

    const float* Wsel = kh ? (dir ? Whh_b : Whh_f) : (dir ? Wih_b : Wih_f);
    const float* bi   = dir ? bih_b : bih_f;
    const float* bh   = dir ? bhh_b : bhh_f;

    __shared__ float gates[2][32][72];   // col-swizzled; all accesses <=2-way banked

    // ---- load B fragments (weights) into registers, kept for all 512 steps ----
    short8 breg[16][2];
    {
        const float* wr0 = Wsel + (size_t)((nt * 2 + 0) * 512 + p * 16 + m15) * 512 + q * 8;
        const float* wr1 = Wsel + (size_t)((nt * 2 + 1) * 512 + p * 16 + m15) * 512 + q * 8;
#pragma unroll
        for (int ks = 0; ks < 16; ++ks) {
            short8 b0, b1;
#pragma unroll
            for (int j = 0; j < 8; ++j) {
                b0[j] = (short)f2bf(wr0[ks * 32 + j]);
                b1[j] = (short)f2bf(wr1[ks * 32 + j]);
            }
            breg[ks][0] = b0; breg[ks][1] = b1;
        }
    }

    // ---- x-thread (tid<128) gate-math state: bias + c-state in REGISTERS ----
    const int gb  = tid >> 2;          // batch 0..31 (valid for tid<128)
    const int gj0 = (tid & 3) * 4;     // 4 h-cols per thread
    const int gqw = (gb & 15) >> 2;    // writer-quad for LDS unswizzle
    float bias_r[4][4];
    float cregs[4] = {0.f, 0.f, 0.f, 0.f};
    float4 hv_prev = {0.f, 0.f, 0.f, 0.f};
    if (kh == 0) {
#pragma unroll
        for (int g = 0; g < 4; ++g)
#pragma unroll
            for (int u = 0; u < 4; ++u) {
                int gr = g * 512 + p * 16 + gj0 + u;
                bias_r[g][u] = bi[gr] + bh[gr];
            }
    }

    unsigned* flg = flags + (size_t)dir * 2048;        // 64 flags per dir (2 lines)
    unsigned short* hexd = h_ex + (size_t)dir * 2 * 16384;

    for (int s = 0; s < 512; ++s) {
        const int t = dir ? (511 - s) : s;
        f32x4 acc00 = {0.f,0.f,0.f,0.f}, acc01 = {0.f,0.f,0.f,0.f};
        f32x4 acc10 = {0.f,0.f,0.f,0.f}, acc11 = {0.f,0.f,0.f,0.f};

        if (kh == 0) {
            // ---- x waves: issue all A loads first (L2-cacheable) ----
            short8 xa0[16], xa1[16];
            const unsigned short* abase = Xb + (size_t)t * 16384;
#pragma unroll
            for (int ks = 0; ks < 16; ++ks) {
                const unsigned short* ap = abase + (size_t)(ks * 4 + q) * 256 + m15 * 8;
                xa0[ks] = *reinterpret_cast<const short8*>(ap);
                xa1[ks] = *reinterpret_cast<const short8*>(ap + 128);
            }
            // deferred out[] store of step s-1 (after loads -> off the load wait)
            if (s > 0) {
                int tp = dir ? (512 - s) : (s - 1);
                float* op = out + (size_t)gb * (512 * 1024) + (size_t)tp * 1024 + dir * 512 + p * 16 + gj0;
                *reinterpret_cast<float4*>(op) = hv_prev;
            }
#pragma unroll
            for (int ks = 0; ks < 16; ++ks) {
                acc00 = __builtin_amdgcn_mfma_f32_16x16x32_bf16(xa0[ks], breg[ks][0], acc00, 0, 0, 0);
                acc01 = __builtin_amdgcn_mfma_f32_16x16x32_bf16(xa0[ks], breg[ks][1], acc01, 0, 0, 0);
                acc10 = __builtin_amdgcn_mfma_f32_16x16x32_bf16(xa1[ks], breg[ks][0], acc10, 0, 0, 0);
                acc11 = __builtin_amdgcn_mfma_f32_16x16x32_bf16(xa1[ks], breg[ks][1], acc11, 0, 0, 0);
            }
        } else {
            // ---- h waves: pure consumers. Poll (no outstanding stores), then batched loads ----
            if (s > 0) {
                const unsigned* fp = flg + ln;   // 64 flags, one per producer wave
                for (;;) {
                    unsigned v = __hip_atomic_load(fp, __ATOMIC_RELAXED, __HIP_MEMORY_SCOPE_AGENT);
                    if (__ballot((int)(v >= (unsigned)s)) == ~0ull) break;
                }
                asm volatile("" ::: "memory");
            }
            const ull* ab = reinterpret_cast<const ull*>(hexd + (size_t)((s + 1) & 1) * 16384);
            ull au0[16][2], au1[16][2];
#pragma unroll
            for (int ks = 0; ks < 16; ++ks) {
                const ull* ap = ab + (ks * 4 + q) * 64 + m15 * 2;
                au0[ks][0] = __hip_atomic_load(ap,      __ATOMIC_RELAXED, __HIP_MEMORY_SCOPE_AGENT);
                au0[ks][1] = __hip_atomic_load(ap + 1,  __ATOMIC_RELAXED, __HIP_MEMORY_SCOPE_AGENT);
                au1[ks][0] = __hip_atomic_load(ap + 32, __ATOMIC_RELAXED, __HIP_MEMORY_SCOPE_AGENT);
                au1[ks][1] = __hip_atomic_load(ap + 33, __ATOMIC_RELAXED, __HIP_MEMORY_SCOPE_AGENT);
            }
#pragma unroll
            for (int ks = 0; ks < 16; ++ks) {
                union { ull u[2]; short8 s8; } a0, a1;
                a0.u[0] = au0[ks][0]; a0.u[1] = au0[ks][1];
                a1.u[0] = au1[ks][0]; a1.u[1] = au1[ks][1];
                acc00 = __builtin_amdgcn_mfma_f32_16x16x32_bf16(a0.s8, breg[ks][0], acc00, 0, 0, 0);
                acc01 = __builtin_amdgcn_mfma_f32_16x16x32_bf16(a0.s8, breg[ks][1], acc01, 0, 0, 0);
                acc10 = __builtin_amdgcn_mfma_f32_16x16x32_bf16(a1.s8, breg[ks][0], acc10, 0, 0, 0);
                acc11 = __builtin_amdgcn_mfma_f32_16x16x32_bf16(a1.s8, breg[ks][1], acc11, 0, 0, 0);
            }
        }

        // ---- dump partials to LDS, col-swizzled by writer quad ----
        {
            int rb  = q * 4;
            int cs0 = ((nt * 32 + m15) + 16 * q) & 63;
            int cs1 = ((nt * 32 + 16 + m15) + 16 * q) & 63;
#pragma unroll
            for (int r = 0; r < 4; ++r) {
                gates[kh][rb + r][cs0]      = acc00[r];
                gates[kh][rb + r][cs1]      = acc01[r];
                gates[kh][16 + rb + r][cs0] = acc10[r];
                gates[kh][16 + rb + r][cs1] = acc11[r];
            }
        }
        __syncthreads();   // sync1: both partials visible

        if (kh == 0) {
            // ---- gate math on x threads only; 4 h-cols each; c-state in regs ----
            float4 xg[4], hg[4];
#pragma unroll
            for (int g = 0; g < 4; ++g) {
                int c0 = ((g + gqw) & 3) * 16 + gj0;   // swizzled, 16B-aligned, contiguous
                xg[g] = *reinterpret_cast<const float4*>(&gates[0][gb][c0]);
                hg[g] = *reinterpret_cast<const float4*>(&gates[1][gb][c0]);
            }
            float hv[4];
#pragma unroll
            for (int u = 0; u < 4; ++u) {
                float ig = xg[0][u] + hg[0][u] + bias_r[0][u];
                float fg = xg[1][u] + hg[1][u] + bias_r[1][u];
                float gg = xg[2][u] + hg[2][u] + bias_r[2][u];
                float og = xg[3][u] + hg[3][u] + bias_r[3][u];
                float cn = sigf(fg) * cregs[u] + sigf(ig) * tanhfast(gg);
                cregs[u] = cn;
                hv[u] = sigf(og) * tanhfast(cn);
            }
            hv_prev = make_float4(hv[0], hv[1], hv[2], hv[3]);
            // packed 4xbf16 write-through store of h for next step
            ull pk = (ull)f2bf(hv[0]) | ((ull)f2bf(hv[1]) << 16)
                   | ((ull)f2bf(hv[2]) << 32) | ((ull)f2bf(hv[3]) << 48);
            ull* dst = reinterpret_cast<ull*>(
                hexd + (size_t)(s & 1) * 16384 + (size_t)(2 * p + (gj0 >> 3)) * 256 + gb * 8 + (gj0 & 7));
            __hip_atomic_store(dst, pk, __ATOMIC_RELAXED, __HIP_MEMORY_SCOPE_AGENT);
            // drain THIS wave's stores, then per-wave flag store (before sync2:
            // flag propagation overlaps the barrier)
            asm volatile("s_waitcnt vmcnt(0)" ::: "memory");
            if (ln == 0) {
                __hip_atomic_store(flg + p * 2 + wv, (unsigned)(s + 1),
                                   __ATOMIC_RELAXED, __HIP_MEMORY_SCOPE_AGENT);
            }
        }
        __syncthreads();   // sync2: gates safe to overwrite next step
    }

    // ---- epilogue: x threads store final-step out + stacked h/c ----
    if (kh == 0) {
        int tl = dir ? 0 : 511;
        float* op = out + (size_t)gb * (512 * 1024) + (size_t)tl * 1024 + dir * 512 + p * 16 + gj0;
        *reinterpret_cast<float4*>(op) = hv_prev;
        float* sh = out + 16777216 + dir * 16384 + gb * 512 + p * 16 + gj0;
        *reinterpret_cast<float4*>(sh) = hv_prev;
        float* sc = out + 16777216 + 32768 + dir * 16384 + gb * 512 + p * 16 + gj0;
        *reinterpret_cast<float4*>(sc) = make_float4(cregs[0], cregs[1], cregs[2], cregs[3]);
    }
}

extern "C" void kernel_launch(void* const* d_in, const int* in_sizes, int n_in,
                              void* d_out, int out_size, void* d_ws, size_t ws_size,
                              hipStream_t stream) {
    const float* X     = (const float*)d_in[0];
    const float* Wih_f = (const float*)d_in[1];
    const float* Whh_f = (const float*)d_in[2];
    const float* bih_f = (const float*)d_in[3];
    const float* bhh_f = (const float*)d_in[4];
    const float* Wih_b = (const float*)d_in[5];
    const float* Whh_b = (const float*)d_in[6];
    const float* bih_b = (const float*)d_in[7];
    const float* bhh_b = (const float*)d_in[8];
    float* out = (float*)d_out;

    unsigned short* Xb   = (unsigned short*)((char*)d_ws + XB_OFF);
    unsigned short* h_ex = (unsigned short*)((char*)d_ws + HEX_OFF);
    unsigned*       flg  = (unsigned*)((char*)d_ws + CTR_OFF);

    // zero h_ex (h_{-1}=0) + flags
    hipMemsetAsync((char*)d_ws + HEX_OFF, 0, (128ull + 64ull) << 10, stream);
    k_xpose<<<8192, 256, 0, stream>>>(X, Xb);
    k_bilstm<<<64, 256, 0, stream>>>(Wih_f, Whh_f, bih_f, bhh_f,
                                     Wih_b, Whh_b, bih_b, bhh_b,
                                     Xb, h_ex, flg, out);
}